// Round 3
// baseline (296.620 us; speedup 1.0000x reference)
//
#include <hip/hip_runtime.h>

typedef __bf16 bf16;
typedef bf16 bf16x4 __attribute__((ext_vector_type(4)));
typedef bf16 bf16x8 __attribute__((ext_vector_type(8)));
typedef float f32x4 __attribute__((ext_vector_type(4)));

#define NND 98      // landmarks
#define KNB 10      // neighbors per node
#define NH 4        // heads
#define CIN 256
#define HC 64
#define CROW_E 132  // bf16 elems per C row (128 data + 4 pad) -> 264 B rows

// Pack W [H][2][CIN][HC] fp32 -> MFMA B-fragment order, bf16:
// Wp[hs][kt(8)][nt(4)][lane(64)][8]  with B[k = kt*32 + (lane>>4)*8 + j][n = nt*16 + (lane&15)]
__global__ __launch_bounds__(256) void prep_wp_kernel(const float* __restrict__ W,
                                                      bf16* __restrict__ Wp) {
  int t = blockIdx.x * 256 + threadIdx.x;
  if (t >= 8 * 8 * 4 * 64) return;
  int lane = t & 63;
  int nt = (t >> 6) & 3;
  int kt = (t >> 8) & 7;
  int hs = t >> 11;
  int n = nt * 16 + (lane & 15);
  int kb = kt * 32 + (lane >> 4) * 8;
  const float* src = W + (hs * CIN + kb) * HC + n;
  bf16x8 v;
#pragma unroll
  for (int j = 0; j < 8; ++j) v[j] = (bf16)src[j * HC];
  *(bf16x8*)(Wp + (long long)t * 8) = v;
}

// One block per (batch item, head). 512 threads = 8 waves.
// Stages x[b] -> LDS in MFMA A-frag order (fused pack), GEMM from LDS + global Wp,
// then per-head softmax-weighted gather epilogue. 3 barriers.
__global__ __launch_bounds__(512, 4) void semgconv_kernel(
    const float* __restrict__ x, const float* __restrict__ e,
    const float* __restrict__ bias, const int* __restrict__ cols,
    const bf16* __restrict__ Wp, float* __restrict__ out, int nwg) {
  // union: xa-tile [7][8][64][8] bf16 (57344 B) during GEMM, then C [112][132] bf16 (29568 B)
  __shared__ __align__(16) unsigned char reg0[7 * 8 * 64 * 8 * 2];
  __shared__ float w_lds[NND * KNB];               // 3920 B
  __shared__ short cols_lds[NND * KNB];            // 1960 B
  __shared__ float diag_lds[NND];                  // 392 B  -> 63616 B total

  const int tid = threadIdx.x;
  // XCD-chunked swizzle: 4 head-blocks of each b land on one XCD, dispatched close in time.
  int n = blockIdx.x;
  int w = ((nwg & 7) == 0) ? ((n & 7) * (nwg >> 3) + (n >> 3)) : n;
  const int b = w >> 2;
  const int h = w & 3;

  const int lane = tid & 63;
  const int wv = tid >> 6;
  const int wm = wv & 3;   // M-group: tiles {2wm, 2wm+1}; wm=3 -> tile 6 only
  const int sh = wv >> 2;  // head-half
  const int mt0 = wm * 2;
  const bool has1 = (mt0 + 1 < 7);  // wave-uniform

  bf16* xa_lds = (bf16*)reg0;

  // ---- phase 1: stage x[b] -> LDS, converting to A-frag order ----
  // frag(mt,kt) element j of lane l = A[row = mt*16 + (l&15)][k = kt*32 + (l>>4)*8 + j]
  // thread map: 8 threads per row (ci = tid&7 -> 16B chunk), 8 consecutive rows per wave
  // -> global reads coalesced (8 x 128B segments per wave), ds_write_b64 spans all 32 banks.
  {
    const float* xb = x + (long long)b * (NND * CIN);
    const int rsub = tid >> 3;  // 0..63
    const int ci = tid & 7;
#pragma unroll
    for (int rp = 0; rp < 2; ++rp) {
      const int row = rp * 64 + rsub;
      if (row < 112) {
        const int mt = row >> 4;
        const int lr = row & 15;
        const int lhi = ci >> 1;        // (c4>>3)&3
        const int j0 = (ci & 1) * 4;    // c4&7
        const int ll = lr | (lhi << 4);
#pragma unroll
        for (int it = 0; it < 8; ++it) {
          const int c4 = (ci + 8 * it) * 4;  // k offset, kt == it
          f32x4 v = {0.f, 0.f, 0.f, 0.f};
          if (row < NND) v = *(const f32x4*)(xb + row * CIN + c4);
          bf16x4 bv;
          bv[0] = (bf16)v[0]; bv[1] = (bf16)v[1]; bv[2] = (bf16)v[2]; bv[3] = (bf16)v[3];
          *(bf16x4*)(xa_lds + ((mt * 8 + it) * 64 + ll) * 8 + j0) = bv;
        }
      }
    }
  }

  // ---- softmax + diag for this head (threads 0..97); overlaps staging stores ----
  if (tid < NND) {
    const int i = tid;
    const int* cp = cols + i * KNB;
    const float* ep = e + (h * NND + i) * KNB;
    float ev[KNB];
    int cv[KNB];
    float mx = -3.0e38f;
#pragma unroll
    for (int j = 0; j < KNB; ++j) { cv[j] = cp[j]; ev[j] = ep[j]; mx = fmaxf(mx, ev[j]); }
    float s = 0.f;
#pragma unroll
    for (int j = 0; j < KNB; ++j) { ev[j] = __expf(ev[j] - mx); s += ev[j]; }
    const float inv = 1.f / s;
    float dg = 0.f;
#pragma unroll
    for (int j = 0; j < KNB; ++j) {
      float wj = ev[j] * inv;
      if (cv[j] == i) { dg = wj; wj = 0.f; }
      w_lds[i * KNB + j] = wj;
      cols_lds[i * KNB + j] = (short)cv[j];
    }
    diag_lds[i] = dg;
  }
  __syncthreads();  // barrier 1: xa-tile ready

  // ---- phase 2: GEMM [112x256 bf16] @ [256x128 bf16] -> fp32 acc ----
  f32x4 acc[2][4] = {};  // [im][nt] -> rows (mt0+im)*16.., cols sh*64 + nt*16 ..
  {
    const bf16* wpl = Wp + ((long long)((h * 2 + sh) * 32) * 64 + lane) * 8;
    const bf16* ax0 = xa_lds + (mt0 * 8 * 64 + lane) * 8;
    const bf16* ax1 = ax0 + 8 * 64 * 8;  // next M-tile
#pragma unroll
    for (int kt = 0; kt < 8; ++kt) {
      bf16x8 afr0 = *(const bf16x8*)(ax0 + kt * 512);  // ds_read_b128, conflict-free
      bf16x8 afr1 = {};
      if (has1) afr1 = *(const bf16x8*)(ax1 + kt * 512);
      bf16x8 bfr[4];
#pragma unroll
      for (int nt = 0; nt < 4; ++nt)
        bfr[nt] = *(const bf16x8*)(wpl + (long long)((kt * 4 + nt) * 64) * 8);
#pragma unroll
      for (int nt = 0; nt < 4; ++nt)
        acc[0][nt] = __builtin_amdgcn_mfma_f32_16x16x32_bf16(afr0, bfr[nt], acc[0][nt], 0, 0, 0);
      if (has1) {
#pragma unroll
        for (int nt = 0; nt < 4; ++nt)
          acc[1][nt] = __builtin_amdgcn_mfma_f32_16x16x32_bf16(afr1, bfr[nt], acc[1][nt], 0, 0, 0);
      }
    }
  }
  __syncthreads();  // barrier 2: all A-frag reads done; reg0 reusable as C

  // ---- acc -> C (bf16 in LDS); rows >= 98 hold zeros (A rows were zeroed) ----
  bf16* C = (bf16*)reg0;
  {
    const int rowb = mt0 * 16 + (lane >> 4) * 4;
    const int colb = sh * 64 + (lane & 15);
#pragma unroll
    for (int im = 0; im < 2; ++im) {
      if (mt0 + im < 7) {
#pragma unroll
        for (int nt = 0; nt < 4; ++nt) {
          const int col = colb + nt * 16;
#pragma unroll
          for (int r = 0; r < 4; ++r)
            C[(rowb + im * 16 + r) * CROW_E + col] = (bf16)acc[im][nt][r];
        }
      }
    }
  }
  __syncthreads();  // barrier 3: C ready

  // ---- gather-aggregate + bias, fp32 store ----
  {
    const int d4 = (tid & 15) * 4;
    const int ig = tid >> 4;  // 0..31
    f32x4 bs = *(const f32x4*)(bias + h * HC + d4);
    float* outb = out + (long long)b * (NND * NH * HC) + h * HC + d4;
#pragma unroll
    for (int p = 0; p < 4; ++p) {
      const int i = p * 32 + ig;
      if (i < NND) {
        f32x4 av = bs;
        const float dg = diag_lds[i];
        bf16x4 c0 = *(const bf16x4*)(C + i * CROW_E + d4);
        av[0] += dg * (float)c0[0];
        av[1] += dg * (float)c0[1];
        av[2] += dg * (float)c0[2];
        av[3] += dg * (float)c0[3];
#pragma unroll
        for (int j = 0; j < KNB; ++j) {
          const float wj = w_lds[i * KNB + j];
          const int cj = cols_lds[i * KNB + j];
          bf16x4 c1 = *(const bf16x4*)(C + cj * CROW_E + HC + d4);
          av[0] += wj * (float)c1[0];
          av[1] += wj * (float)c1[1];
          av[2] += wj * (float)c1[2];
          av[3] += wj * (float)c1[3];
        }
        *(f32x4*)(outb + (long long)i * (NH * HC)) = av;
      }
    }
  }
}

extern "C" void kernel_launch(void* const* d_in, const int* in_sizes, int n_in,
                              void* d_out, int out_size, void* d_ws, size_t ws_size,
                              hipStream_t stream) {
  const float* x    = (const float*)d_in[0];
  const float* W    = (const float*)d_in[1];
  const float* e    = (const float*)d_in[2];
  const float* bias = (const float*)d_in[3];
  // d_in[4] = rows: unused (fixed pattern: row i owns edges i*K .. i*K+K-1)
  const int* cols   = (const int*)d_in[5];
  float* out        = (float*)d_out;
  bf16* Wp          = (bf16*)d_ws;   // 131072 bf16 = 256 KiB of scratch

  int B = in_sizes[0] / (NND * CIN);  // 1024

  prep_wp_kernel<<<64, 256, 0, stream>>>(W, Wp);
  const int nwg = B * NH;
  semgconv_kernel<<<nwg, 512, 0, stream>>>(x, e, bias, cols, Wp, out, nwg);
}

// Round 4
// 240.337 us; speedup vs baseline: 1.2342x; 1.2342x over previous
//
#include <hip/hip_runtime.h>

typedef __bf16 bf16;
typedef bf16 bf16x4 __attribute__((ext_vector_type(4)));
typedef bf16 bf16x8 __attribute__((ext_vector_type(8)));
typedef float f32x4 __attribute__((ext_vector_type(4)));

#define NND 98      // landmarks
#define KNB 10      // neighbors per node
#define NH 4        // heads
#define CIN 256
#define HC 64
#define CROW_E 132  // bf16 elems per C row (128 data + 4 pad) -> 264 B rows
#define WP_BYTES 262144  // Wp region at front of workspace
#define XA_TILE (7 * 8 * 64 * 8)  // bf16 elems per batch item in xa

__device__ __forceinline__ bf16x8 load_a8(const float* p) {
  f32x4 u = *(const f32x4*)p;
  f32x4 v = *(const f32x4*)(p + 4);
  bf16x8 a;
  a[0] = (bf16)u[0]; a[1] = (bf16)u[1]; a[2] = (bf16)u[2]; a[3] = (bf16)u[3];
  a[4] = (bf16)v[0]; a[5] = (bf16)v[1]; a[6] = (bf16)v[2]; a[7] = (bf16)v[3];
  return a;
}

// Blocks 0..63: pack W [H][2][CIN][HC] fp32 -> MFMA B-frag order bf16:
//   Wp[hs][kt(8)][nt(4)][lane(64)][8], B[k=kt*32+(lane>>4)*8+j][n=nt*16+(lane&15)]
// Blocks 64.. : pack x [B][98][256] fp32 -> MFMA A-frag order bf16:
//   xa[b][mt(7)][kt(8)][lane(64)][8], A[row=mt*16+(lane&15)][k=kt*32+(lane>>4)*8+j]
//   rows >= 98 zero-filled.
__global__ __launch_bounds__(256) void prep_kernel(const float* __restrict__ W,
                                                   bf16* __restrict__ Wp,
                                                   const float* __restrict__ x,
                                                   bf16* __restrict__ xa, int B) {
  if (blockIdx.x < 64) {
    int t = blockIdx.x * 256 + threadIdx.x;
    if (t >= 8 * 8 * 4 * 64) return;
    int lane = t & 63;
    int nt = (t >> 6) & 3;
    int kt = (t >> 8) & 7;
    int hs = t >> 11;
    int n = nt * 16 + (lane & 15);
    int kb = kt * 32 + (lane >> 4) * 8;
    const float* src = W + (hs * CIN + kb) * HC + n;
    bf16x8 v;
#pragma unroll
    for (int j = 0; j < 8; ++j) v[j] = (bf16)src[j * HC];
    *(bf16x8*)(Wp + (long long)t * 8) = v;
    return;
  }
  int u = (blockIdx.x - 64) * 256 + threadIdx.x;
  int total = B * 7 * 8 * 64;
  if (u >= total) return;
  int lane = u & 63;
  int kt = (u >> 6) & 7;
  int v = u >> 9;           // b*7 + mt
  int b = v / 7;
  int mt = v - b * 7;
  int row = mt * 16 + (lane & 15);
  int k0 = kt * 32 + (lane >> 4) * 8;
  bf16x8 a = {};
  if (row < NND) a = load_a8(x + ((long long)b * NND + row) * CIN + k0);
  *(bf16x8*)(xa + (long long)u * 8) = a;   // writes fully coalesced
}

// One block per (batch-PAIR, head). 512 threads = 8 waves.
// Wave wv: wm = wv&3 (M-group of 2 tiles), sh = wv>>2 (head-half: 0 -> h0, 1 -> h1).
// Each wave accumulates BOTH batch items of the pair -> per kt-step:
// 8 global b128 loads feed 16 MFMAs (2x density vs BB=1). Single barrier.
template <bool XA>
__global__ __launch_bounds__(512, 4) void semgconv_kernel(
    const float* __restrict__ x, const bf16* __restrict__ xa,
    const float* __restrict__ e, const float* __restrict__ bias,
    const int* __restrict__ cols, const bf16* __restrict__ Wp,
    float* __restrict__ out, int nwg) {
  __shared__ __align__(16) bf16 C2[2][112 * CROW_E]; // 59136 B
  __shared__ float w_lds[NND * KNB];                 // 3920 B
  __shared__ short cols_lds[NND * KNB];              // 1960 B
  __shared__ float diag_lds[NND];                    // 392 B  -> 65408 B total

  const int tid = threadIdx.x;
  // XCD-chunked swizzle: the 4 head-blocks of each pair land on one XCD (shared L2 for xa).
  int n = blockIdx.x;
  int w = ((nwg & 7) == 0) ? ((n & 7) * (nwg >> 3) + (n >> 3)) : n;
  const int bp = w >> 2;       // batch-pair index
  const int h = w & 3;
  const int b0 = bp * 2;

  const int lane = tid & 63;
  const int wv = tid >> 6;
  const int wm = wv & 3;   // M-group: tiles {2wm, 2wm+1}; wm=3 -> tile 6 only
  const int sh = wv >> 2;  // head-half
  const int mt0 = wm * 2;
  const bool has1 = (mt0 + 1 < 7);  // wave-uniform

  // ---- softmax + diag for this head (threads 0..97); overlaps GEMM loads ----
  if (tid < NND) {
    const int i = tid;
    const int* cp = cols + i * KNB;
    const float* ep = e + (h * NND + i) * KNB;
    float ev[KNB];
    int cv[KNB];
    float mx = -3.0e38f;
#pragma unroll
    for (int j = 0; j < KNB; ++j) { cv[j] = cp[j]; ev[j] = ep[j]; mx = fmaxf(mx, ev[j]); }
    float s = 0.f;
#pragma unroll
    for (int j = 0; j < KNB; ++j) { ev[j] = __expf(ev[j] - mx); s += ev[j]; }
    const float inv = 1.f / s;
    float dg = 0.f;
#pragma unroll
    for (int j = 0; j < KNB; ++j) {
      float wj = ev[j] * inv;
      if (cv[j] == i) { dg = wj; wj = 0.f; }
      w_lds[i * KNB + j] = wj;
      cols_lds[i * KNB + j] = (short)cv[j];
    }
    diag_lds[i] = dg;
  }

  // ---- GEMM: 2 x [112x256 bf16] @ [256x128 bf16] -> fp32 acc ----
  f32x4 acc[2][2][4] = {};  // [item][im][nt]
  {
    const bf16* wpl = Wp + ((long long)((h * 2 + sh) * 32) * 64 + lane) * 8;
    if (XA) {
      const bf16* ax0 = xa + (((long long)b0 * 7 + mt0) * 8 * 64 + lane) * 8;
      const bf16* ax1 = ax0 + XA_TILE;  // item b0+1
#pragma unroll
      for (int kt = 0; kt < 8; ++kt) {
        bf16x8 a00 = *(const bf16x8*)(ax0 + kt * 512);
        bf16x8 a10 = *(const bf16x8*)(ax1 + kt * 512);
        bf16x8 a01 = {}, a11 = {};
        if (has1) {
          a01 = *(const bf16x8*)(ax0 + 4096 + kt * 512);
          a11 = *(const bf16x8*)(ax1 + 4096 + kt * 512);
        }
        bf16x8 bfr[4];
#pragma unroll
        for (int nt = 0; nt < 4; ++nt)
          bfr[nt] = *(const bf16x8*)(wpl + (long long)((kt * 4 + nt) * 64) * 8);
#pragma unroll
        for (int nt = 0; nt < 4; ++nt) {
          acc[0][0][nt] = __builtin_amdgcn_mfma_f32_16x16x32_bf16(a00, bfr[nt], acc[0][0][nt], 0, 0, 0);
          acc[1][0][nt] = __builtin_amdgcn_mfma_f32_16x16x32_bf16(a10, bfr[nt], acc[1][0][nt], 0, 0, 0);
        }
        if (has1) {
#pragma unroll
          for (int nt = 0; nt < 4; ++nt) {
            acc[0][1][nt] = __builtin_amdgcn_mfma_f32_16x16x32_bf16(a01, bfr[nt], acc[0][1][nt], 0, 0, 0);
            acc[1][1][nt] = __builtin_amdgcn_mfma_f32_16x16x32_bf16(a11, bfr[nt], acc[1][1][nt], 0, 0, 0);
          }
        }
      }
    } else {
      // fallback (workspace too small for xa): direct fp32 loads (slow but correct)
      const int r0 = mt0 * 16 + (lane & 15);
      const int kb = (lane >> 4) * 8;
      const bool ok0 = (r0 < NND);
#pragma unroll
      for (int kt = 0; kt < 8; ++kt) {
        bf16x8 afr[2][2];
#pragma unroll
        for (int it2 = 0; it2 < 2; ++it2) {
          const float* ap = x + ((long long)(b0 + it2) * NND + r0) * CIN + kb;
          afr[it2][0] = ok0 ? load_a8(ap + kt * 32) : bf16x8{};
          afr[it2][1] = has1 ? load_a8(ap + 16 * CIN + kt * 32) : bf16x8{};
        }
        bf16x8 bfr[4];
#pragma unroll
        for (int nt = 0; nt < 4; ++nt)
          bfr[nt] = *(const bf16x8*)(wpl + (long long)((kt * 4 + nt) * 64) * 8);
#pragma unroll
        for (int it2 = 0; it2 < 2; ++it2)
#pragma unroll
          for (int im = 0; im < 2; ++im)
            if (im == 0 || has1)
#pragma unroll
              for (int nt = 0; nt < 4; ++nt)
                acc[it2][im][nt] = __builtin_amdgcn_mfma_f32_16x16x32_bf16(
                    afr[it2][im], bfr[nt], acc[it2][im][nt], 0, 0, 0);
      }
    }
  }

  // ---- acc -> C (bf16 in LDS); rows >= 98 hold zeros ----
  {
    const int rowb = mt0 * 16 + (lane >> 4) * 4;
    const int colb = sh * 64 + (lane & 15);
#pragma unroll
    for (int it2 = 0; it2 < 2; ++it2) {
#pragma unroll
      for (int im = 0; im < 2; ++im) {
        if (mt0 + im < 7) {
#pragma unroll
          for (int nt = 0; nt < 4; ++nt) {
            const int col = colb + nt * 16;
#pragma unroll
            for (int r = 0; r < 4; ++r)
              C2[it2][(rowb + im * 16 + r) * CROW_E + col] = (bf16)acc[it2][im][nt][r];
          }
        }
      }
    }
  }
  __syncthreads();  // the only barrier: C2 / w / cols / diag ready

  // ---- gather-aggregate + bias, fp32 store (both items) ----
  {
    const int d4 = (tid & 15) * 4;
    const int ig = tid >> 4;  // 0..31
    f32x4 bs = *(const f32x4*)(bias + h * HC + d4);
#pragma unroll
    for (int it2 = 0; it2 < 2; ++it2) {
      const bf16* C = C2[it2];
      float* outb = out + (long long)(b0 + it2) * (NND * NH * HC) + h * HC + d4;
#pragma unroll
      for (int p = 0; p < 4; ++p) {
        const int i = p * 32 + ig;
        if (i < NND) {
          f32x4 av = bs;
          const float dg = diag_lds[i];
          bf16x4 c0 = *(const bf16x4*)(C + i * CROW_E + d4);
          av[0] += dg * (float)c0[0];
          av[1] += dg * (float)c0[1];
          av[2] += dg * (float)c0[2];
          av[3] += dg * (float)c0[3];
#pragma unroll
          for (int j = 0; j < KNB; ++j) {
            const float wj = w_lds[i * KNB + j];
            const int cj = cols_lds[i * KNB + j];
            bf16x4 c1 = *(const bf16x4*)(C + cj * CROW_E + HC + d4);
            av[0] += wj * (float)c1[0];
            av[1] += wj * (float)c1[1];
            av[2] += wj * (float)c1[2];
            av[3] += wj * (float)c1[3];
          }
          *(f32x4*)(outb + (long long)i * (NH * HC)) = av;
        }
      }
    }
  }
}

extern "C" void kernel_launch(void* const* d_in, const int* in_sizes, int n_in,
                              void* d_out, int out_size, void* d_ws, size_t ws_size,
                              hipStream_t stream) {
  const float* x    = (const float*)d_in[0];
  const float* W    = (const float*)d_in[1];
  const float* e    = (const float*)d_in[2];
  const float* bias = (const float*)d_in[3];
  // d_in[4] = rows: unused (fixed pattern: row i owns edges i*K .. i*K+K-1)
  const int* cols   = (const int*)d_in[5];
  float* out        = (float*)d_out;

  int B = in_sizes[0] / (NND * CIN);  // 1024

  bf16* Wp = (bf16*)d_ws;
  bf16* xa = (bf16*)((char*)d_ws + WP_BYTES);
  const long long xa_bytes = (long long)B * XA_TILE * (long long)sizeof(bf16);
  const bool use_xa = (long long)ws_size >= (long long)WP_BYTES + xa_bytes;

  int xa_blocks = use_xa ? (B * 7 * 8 * 64) / 256 : 0;
  prep_kernel<<<64 + xa_blocks, 256, 0, stream>>>(W, Wp, x, xa, B);

  const int nwg = (B / 2) * NH;  // one block per (batch-pair, head)
  if (use_xa)
    semgconv_kernel<true><<<nwg, 512, 0, stream>>>(x, xa, e, bias, cols, Wp, out, nwg);
  else
    semgconv_kernel<false><<<nwg, 512, 0, stream>>>(x, xa, e, bias, cols, Wp, out, nwg);
}